// Round 1
// baseline (1781.794 us; speedup 1.0000x reference)
//
#include <hip/hip_runtime.h>
#include <hip/hip_bf16.h>
#include <math.h>

// ---------------------------------------------------------------------------
// RecSys_83391085019409: BiLSTM (fused, persistent per-batch-chunk) + conv/fc
// collapsed into one GEMM per mat + scalar loss.
// B=4096 T=50 D=256 H=128 C=128
// ---------------------------------------------------------------------------

using short8   = __attribute__((ext_vector_type(8))) short;
using float4_v = __attribute__((ext_vector_type(4))) float;
using ushort4_v= __attribute__((ext_vector_type(4))) unsigned short;

// ---- workspace layout (bytes) ----
#define WS_WC     0u          // bf16 Wc frags: 2 dirs * 12kb*32nt*64lane*8e *2B = 786432
#define WS_BIAS   786432u     // permuted biases: 2*512*4 = 4096
#define WS_WBIG   790528u     // conv big-W frags: 2 sets * 24*48*64*8 *2B = 2359296
#define WS_CBIAS  3149824u    // 2*768*4
#define WS_WPROD  3155968u    // 2*768*4
#define WS_K0     3162112u    // 2 floats (+pad 256)
#define WS_TGT    3162368u    // 4*4096*4 = 65536
#define WS_EMBQ   3227904u    // 4096*256*4
#define WS_EMBQP  7422208u    // 4096*256*4
#define WS_LOW    11616512u   // 4096*4
#define WS_HIGH   11632896u
#define WS_PTS    11649280u
#define WS_END    11665664u

__device__ __forceinline__ unsigned short f2bf(float f) {
  union { float f; unsigned u; } v; v.f = f;
  unsigned r = v.u + 0x7FFFu + ((v.u >> 16) & 1u);
  return (unsigned short)(r >> 16);
}
__device__ __forceinline__ float sigm(float x) { return 1.f / (1.f + __expf(-x)); }
__device__ __forceinline__ float tanh_f(float x) {
  x = fminf(15.f, fmaxf(-15.f, x));
  float e = __expf(2.f * x);
  return (e - 1.f) / (e + 1.f);
}

// Column permutation for the LSTM gate matrix (N=512):
// m = wblk*64 + g*16 + u  ->  orig n = g*128 + wblk*16 + u
// so each 64-col group holds all 4 gates for 16 hidden units (lane-local gates).
__device__ __forceinline__ int lstm_orig_n(int m) {
  return ((m >> 4) & 3) * 128 + (m >> 6) * 16 + (m & 15);
}

// ---------------------------------------------------------------------------
__global__ void prep_kernel(
    const float* __restrict__ wihf, const float* __restrict__ whhf, const float* __restrict__ bf_,
    const float* __restrict__ wihb, const float* __restrict__ whhb, const float* __restrict__ bb_,
    const float* __restrict__ c1w, const float* __restrict__ c1b,
    const float* __restrict__ c2w, const float* __restrict__ c2b,
    const float* __restrict__ c3w, const float* __restrict__ c3b,
    const float* __restrict__ p1w, const float* __restrict__ p1b,
    const float* __restrict__ p2w, const float* __restrict__ p2b,
    const float* __restrict__ p3w, const float* __restrict__ p3b,
    const float* __restrict__ fc1w, const float* __restrict__ fc1b,
    const float* __restrict__ fc2w, const float* __restrict__ fc2b,
    const float* __restrict__ fp1w, const float* __restrict__ fp1b,
    const float* __restrict__ fp2w, const float* __restrict__ fp2b,
    const int* __restrict__ qlen, const int* __restrict__ qplen,
    char* __restrict__ ws)
{
  unsigned short* wc   = (unsigned short*)(ws + WS_WC);
  float*          bsp  = (float*)(ws + WS_BIAS);
  unsigned short* wbig = (unsigned short*)(ws + WS_WBIG);
  float*          cbias= (float*)(ws + WS_CBIAS);
  float*          wprod= (float*)(ws + WS_WPROD);
  float*          k0   = (float*)(ws + WS_K0);
  int*            tgt  = (int*)(ws + WS_TGT);
  float*          embq = (float*)(ws + WS_EMBQ);
  float*          embqp= (float*)(ws + WS_EMBQP);

  const long N0 = 393216;    // wc elems
  const long N1 = 1024;      // biases
  const long N2 = 1179648;   // wbig elems
  const long N3 = 1536;      // cbias
  const long N4 = 1536;      // wprod
  const long N5 = 16384;     // tgt
  const long N6 = 2097152;   // emb zero
  const long total = N0 + N1 + N2 + N3 + N4 + N5 + N6 + 2;

  for (long i = (long)blockIdx.x * blockDim.x + threadIdx.x; i < total;
       i += (long)gridDim.x * blockDim.x) {
    long idx = i;
    if (idx < N0) {
      long t = idx;
      int e = t & 7; t >>= 3;
      int l = t & 63; t >>= 6;
      int nt = (int)(t % 32); t /= 32;
      int kb = (int)(t % 12); t /= 12;
      int dir = (int)t;
      int k = kb * 32 + (l >> 4) * 8 + e;        // 0..383
      int m = nt * 16 + (l & 15);                // 0..511 (permuted col)
      int n = lstm_orig_n(m);
      const float* wih = dir ? wihb : wihf;
      const float* whh = dir ? whhb : whhf;
      float v = (k < 256) ? wih[n * 256 + k] : whh[n * 128 + (k - 256)];
      wc[idx] = f2bf(v);
    } else if ((idx -= N0) < N1) {
      int dir = (int)(idx >> 9); int m = (int)(idx & 511);
      bsp[idx] = (dir ? bb_ : bf_)[lstm_orig_n(m)];
    } else if ((idx -= N1) < N2) {
      long t = idx;
      int e = t & 7; t >>= 3;
      int l = t & 63; t >>= 6;
      int nt = (int)(t % 48); t /= 48;
      int kb = (int)(t % 24); t /= 24;
      int set = (int)t;
      int k = kb * 32 + (l >> 4) * 8 + e;        // 0..767
      int n = nt * 16 + (l & 15);                // 0..767
      int tau = n >> 7, c = n & 127;
      int r3 = k >> 8, dd = k & 255;
      const float* w1 = set ? p1w : c1w;
      const float* w2 = set ? p2w : c2w;
      const float* w3 = set ? p3w : c3w;
      float v = 0.f;
      if (tau < 3)        { if (r3 == tau) v = w1[c * 256 + dd]; }
      else if (tau == 3)  { if (r3 <= 1)   v = w2[(c * 2 + r3) * 256 + dd]; }
      else if (tau == 4)  { if (r3 >= 1)   v = w2[(c * 2 + r3 - 1) * 256 + dd]; }
      else                {                v = w3[(c * 3 + r3) * 256 + dd]; }
      wbig[idx] = f2bf(v);
    } else if ((idx -= N2) < N3) {
      int set = (int)(idx / 768); int n = (int)(idx % 768);
      int tau = n >> 7, c = n & 127;
      const float* b1 = set ? p1b : c1b;
      const float* b2 = set ? p2b : c2b;
      const float* b3 = set ? p3b : c3b;
      cbias[idx] = (tau < 3) ? b1[c] : (tau < 5 ? b2[c] : b3[c]);
    } else if ((idx -= N3) < N4) {
      int set = (int)(idx / 768); int n = (int)(idx % 768);
      int tau = n >> 7, c = n & 127;
      wprod[idx] = (set ? fp1w : fc1w)[tau] * (set ? fp2w : fc2w)[c];
    } else if ((idx -= N4) < N5) {
      int seqi = (int)(idx >> 13);
      int rem  = (int)(idx & 8191);
      int dir = rem >> 12, b = rem & 4095;
      int L = seqi ? qplen[b] : qlen[b];
      tgt[idx] = (L < 1) ? -1 : (dir ? (50 - L) : (L - 1));
    } else if ((idx -= N5) < N6) {
      if (idx < 1048576) embq[idx] = 0.f; else embqp[idx - 1048576] = 0.f;
    } else {
      idx -= N6;  // 0 or 1 -> K0 constants
      const float* f2 = idx ? fp2w : fc2w;
      float s = 0.f;
      for (int c = 0; c < 128; c++) s += f2[c];
      k0[idx] = (idx ? fp1b[0] : fc1b[0]) * s + (idx ? fp2b[0] : fc2b[0]);
    }
  }
}

// ---------------------------------------------------------------------------
// Fused BiLSTM. grid = 256 blocks: run = blk>>6 (0:q-fwd 1:q-bwd 2:qp-fwd
// 3:qp-bwd), grp = blk&63 owns rows [grp*64, grp*64+64). 512 threads (8 waves).
// Wave wv owns all 64 rows x 64 permuted cols [wv*64, wv*64+64)
//   = gates {i,f,g,o} x hidden units [wv*16, wv*16+16)  -> lane-local gates.
// ---------------------------------------------------------------------------
__global__ __launch_bounds__(512) void lstm_kernel(
    const float* __restrict__ rank_q, const float* __restrict__ rank_qp,
    char* __restrict__ ws)
{
  __shared__ unsigned short A_lds[64 * 392];  // 392 shorts/row: 256 x | 128 h | 8 pad
  const int tid  = threadIdx.x;
  const int lane = tid & 63;
  const int wv   = tid >> 6;
  const int l4   = lane >> 4;
  const int lm   = lane & 15;

  const int run   = blockIdx.x >> 6;
  const int grp   = blockIdx.x & 63;
  const int dir   = run & 1;
  const int seqi  = run >> 1;
  const int rowg0 = grp * 64;
  const float* xsrc = seqi ? rank_qp : rank_q;

  const unsigned short* wc = (const unsigned short*)(ws + WS_WC) + (size_t)dir * 196608;
  const float* biasp = (const float*)(ws + WS_BIAS) + dir * 512;
  const int*   tgt   = (const int*)(ws + WS_TGT) + (seqi * 2 + dir) * 4096;
  float*       emb   = (float*)(ws + (seqi ? WS_EMBQP : WS_EMBQ));

  float bv[4];
  #pragma unroll
  for (int g = 0; g < 4; g++) bv[g] = biasp[(wv * 4 + g) * 16 + lm];

  int tg[4][4];
  #pragma unroll
  for (int rti = 0; rti < 4; rti++)
    #pragma unroll
    for (int r = 0; r < 4; r++)
      tg[rti][r] = tgt[rowg0 + rti * 16 + l4 * 4 + r];

  float cst[4][4];
  #pragma unroll
  for (int rti = 0; rti < 4; rti++)
    #pragma unroll
    for (int r = 0; r < 4; r++) cst[rti][r] = 0.f;

  // zero h region (+pad)
  for (int i = tid; i < 64 * 136; i += 512) {
    int rr = i / 136, cc = i - rr * 136;
    A_lds[rr * 392 + 256 + cc] = 0;
  }
  const int rowx = tid >> 3;
  const int dseg = (tid & 7) * 32;
  {
    int t0 = dir ? 49 : 0;
    const float* src = xsrc + ((size_t)(rowg0 + rowx) * 50 + t0) * 256 + dseg;
    #pragma unroll
    for (int j = 0; j < 8; j++) {
      float4_v v = *(const float4_v*)(src + j * 4);
      ushort4_v pk; pk.x = f2bf(v.x); pk.y = f2bf(v.y); pk.z = f2bf(v.z); pk.w = f2bf(v.w);
      *(ushort4_v*)(&A_lds[rowx * 392 + dseg + j * 4]) = pk;
    }
  }
  __syncthreads();

  const int hu = wv * 16 + lm;

  for (int s = 0; s < 50; s++) {
    // prefetch next x-tile into registers (hidden under MFMA phase)
    float4_v xp[8];
    const int sn = s + 1;
    if (sn < 50) {
      int tn = dir ? (49 - sn) : sn;
      const float* src = xsrc + ((size_t)(rowg0 + rowx) * 50 + tn) * 256 + dseg;
      #pragma unroll
      for (int j = 0; j < 8; j++) xp[j] = *(const float4_v*)(src + j * 4);
    }

    float4_v acc[4][4];
    #pragma unroll
    for (int i_ = 0; i_ < 4; i_++)
      #pragma unroll
      for (int j_ = 0; j_ < 4; j_++) acc[i_][j_] = float4_v{0.f, 0.f, 0.f, 0.f};

    #pragma unroll
    for (int kb = 0; kb < 12; kb++) {
      // A frags: row = rt*16 + lm, k = kb*32 + l4*8 + e (same k-map as B)
      short8 a0 = *(const short8*)(&A_lds[( 0 + lm) * 392 + kb * 32 + l4 * 8]);
      short8 a1 = *(const short8*)(&A_lds[(16 + lm) * 392 + kb * 32 + l4 * 8]);
      short8 a2 = *(const short8*)(&A_lds[(32 + lm) * 392 + kb * 32 + l4 * 8]);
      short8 a3 = *(const short8*)(&A_lds[(48 + lm) * 392 + kb * 32 + l4 * 8]);
      #pragma unroll
      for (int j = 0; j < 4; j++) {
        const short8 bfrag =
            *(const short8*)(wc + ((size_t)(kb * 32 + wv * 4 + j) * 64 + lane) * 8);
        acc[0][j] = __builtin_amdgcn_mfma_f32_16x16x32_bf16(a0, bfrag, acc[0][j], 0, 0, 0);
        acc[1][j] = __builtin_amdgcn_mfma_f32_16x16x32_bf16(a1, bfrag, acc[1][j], 0, 0, 0);
        acc[2][j] = __builtin_amdgcn_mfma_f32_16x16x32_bf16(a2, bfrag, acc[2][j], 0, 0, 0);
        acc[3][j] = __builtin_amdgcn_mfma_f32_16x16x32_bf16(a3, bfrag, acc[3][j], 0, 0, 0);
      }
    }
    __syncthreads();

    // gates: fully lane-local (frag j == gate j for this wave's hu)
    #pragma unroll
    for (int rti = 0; rti < 4; rti++) {
      #pragma unroll
      for (int r = 0; r < 4; r++) {
        float zi = acc[rti][0][r] + bv[0];
        float zf = acc[rti][1][r] + bv[1];
        float zg = acc[rti][2][r] + bv[2];
        float zo = acc[rti][3][r] + bv[3];
        float ig = sigm(zi), fg = sigm(zf), og = sigm(zo);
        float gg = tanh_f(zg);
        float cn = fg * cst[rti][r] + ig * gg;
        cst[rti][r] = cn;
        float hn = og * tanh_f(cn);
        int row = rti * 16 + l4 * 4 + r;
        A_lds[row * 392 + 256 + hu] = f2bf(hn);
        if (s == tg[rti][r])
          emb[(size_t)(rowg0 + row) * 256 + dir * 128 + hu] = hn;
      }
    }
    // stage next x tile
    if (sn < 50) {
      #pragma unroll
      for (int j = 0; j < 8; j++) {
        ushort4_v pk;
        pk.x = f2bf(xp[j].x); pk.y = f2bf(xp[j].y); pk.z = f2bf(xp[j].z); pk.w = f2bf(xp[j].w);
        *(ushort4_v*)(&A_lds[rowx * 392 + dseg + j * 4]) = pk;
      }
    }
    __syncthreads();
  }
}

// ---------------------------------------------------------------------------
// All convs + relu + fc1 + fc2 per mat as one GEMM: [32 rows x 768] @ [768x768]
// with post-ReLU scalar fold (wprod) and per-row reduction.
// grid = (128 row-groups, 3 mats), 256 threads (4 waves).
// ---------------------------------------------------------------------------
__global__ __launch_bounds__(256) void conv_kernel(
    const float* __restrict__ ru, const float* __restrict__ au,
    const int* __restrict__ r_idx, const int* __restrict__ a_idx,
    const int* __restrict__ acc_idx, const int* __restrict__ rp_idx,
    const int* __restrict__ ap_idx, char* __restrict__ ws)
{
  __shared__ unsigned short Atile[32 * 776];   // 768 + 8 pad shorts per row
  __shared__ float red[32][2];
  const int tid = threadIdx.x, lane = tid & 63, wv = tid >> 6;
  const int l4 = lane >> 4, lm = lane & 15;
  const int mgrp = blockIdx.x;
  const int mat  = blockIdx.y;           // 0 low, 1 high, 2 point
  const int set  = (mat == 2) ? 1 : 0;
  const unsigned short* wbig = (const unsigned short*)(ws + WS_WBIG) + (size_t)set * 589824;
  const float* cbias = (const float*)(ws + WS_CBIAS) + set * 768;
  const float* wprod = (const float*)(ws + WS_WPROD) + set * 768;
  const float  K0    = ((const float*)(ws + WS_K0))[set];
  const float* embq  = (const float*)(ws + WS_EMBQ);
  const float* embqp = (const float*)(ws + WS_EMBQP);
  float* outp = (float*)(ws + (mat == 0 ? WS_LOW : (mat == 1 ? WS_HIGH : WS_PTS)));

  const int b0 = mgrp * 32;
  {
    const int rowr = tid >> 3;
    const int seg  = (tid & 7) * 96;
    const int b = b0 + rowr;
    const float *s0, *s1, *s2;
    if (mat == 0)      { s0 = ru + (size_t)r_idx[b] * 256;  s1 = embq  + (size_t)b * 256; s2 = au + (size_t)a_idx[b] * 256; }
    else if (mat == 1) { s0 = ru + (size_t)r_idx[b] * 256;  s1 = embq  + (size_t)b * 256; s2 = au + (size_t)acc_idx[b] * 256; }
    else               { s0 = ru + (size_t)rp_idx[b] * 256; s1 = embqp + (size_t)b * 256; s2 = ru + (size_t)ap_idx[b] * 256; }
    #pragma unroll
    for (int j = 0; j < 24; j++) {
      int k = seg + j * 4;
      int r3 = k >> 8, dd = k & 255;
      const float* src = (r3 == 0) ? s0 : (r3 == 1 ? s1 : s2);
      float4_v v = *(const float4_v*)(src + dd);
      ushort4_v pk; pk.x = f2bf(v.x); pk.y = f2bf(v.y); pk.z = f2bf(v.z); pk.w = f2bf(v.w);
      *(ushort4_v*)(&Atile[rowr * 776 + k]) = pk;
    }
  }
  __syncthreads();

  const int rt  = wv & 1;
  const int ntb = (wv >> 1) * 24;
  float4_v acc[24];
  #pragma unroll
  for (int j = 0; j < 24; j++) acc[j] = float4_v{0.f, 0.f, 0.f, 0.f};
  const int arow = rt * 16 + lm;
  #pragma unroll 1
  for (int kb = 0; kb < 24; kb++) {
    short8 a = *(const short8*)(&Atile[arow * 776 + kb * 32 + l4 * 8]);
    #pragma unroll
    for (int j = 0; j < 24; j++) {
      short8 bfrag = *(const short8*)(wbig + ((size_t)(kb * 48 + ntb + j) * 64 + lane) * 8);
      acc[j] = __builtin_amdgcn_mfma_f32_16x16x32_bf16(a, bfrag, acc[j], 0, 0, 0);
    }
  }
  float rs[4] = {0.f, 0.f, 0.f, 0.f};
  #pragma unroll
  for (int j = 0; j < 24; j++) {
    int n = (ntb + j) * 16 + lm;
    float cb = cbias[n], wp = wprod[n];
    #pragma unroll
    for (int r = 0; r < 4; r++)
      rs[r] += fmaxf(acc[j][r] + cb, 0.f) * wp;
  }
  #pragma unroll
  for (int r = 0; r < 4; r++) {
    float v = rs[r];
    v += __shfl_xor(v, 1);
    v += __shfl_xor(v, 2);
    v += __shfl_xor(v, 4);
    v += __shfl_xor(v, 8);
    rs[r] = v;
  }
  if (lm == 0) {
    int rloc = rt * 16 + l4 * 4;
    #pragma unroll
    for (int r = 0; r < 4; r++) red[rloc + r][wv >> 1] = rs[r];
  }
  __syncthreads();
  if (tid < 32) outp[b0 + tid] = red[tid][0] + red[tid][1] + K0;
}

// ---------------------------------------------------------------------------
__global__ void loss_kernel(const float* __restrict__ point, char* __restrict__ ws,
                            float* __restrict__ out)
{
  __shared__ float ra[256], rb[256];
  const float* low  = (const float*)(ws + WS_LOW);
  const float* high = (const float*)(ws + WS_HIGH);
  const float* pts  = (const float*)(ws + WS_PTS);
  int tid = threadIdx.x;
  float a = 0.f, b = 0.f;
  for (int i = tid; i < 4096; i += 256) {
    a += sigm(low[i] - high[i]);
    b += sigm(fabsf(pts[i] - point[i]));
  }
  ra[tid] = a; rb[tid] = b;
  __syncthreads();
  for (int off = 128; off > 0; off >>= 1) {
    if (tid < off) { ra[tid] += ra[tid + off]; rb[tid] += rb[tid + off]; }
    __syncthreads();
  }
  if (tid == 0) out[0] = 0.8f * ra[0] + 0.2f * rb[0];
}

// ---------------------------------------------------------------------------
extern "C" void kernel_launch(void* const* d_in, const int* in_sizes, int n_in,
                              void* d_out, int out_size, void* d_ws, size_t ws_size,
                              hipStream_t stream) {
  (void)in_sizes; (void)n_in; (void)out_size;
  const float* ru   = (const float*)d_in[0];
  const float* au   = (const float*)d_in[1];
  const float* wihf = (const float*)d_in[2];
  const float* whhf = (const float*)d_in[3];
  const float* bf_  = (const float*)d_in[4];
  const float* wihb = (const float*)d_in[5];
  const float* whhb = (const float*)d_in[6];
  const float* bb_  = (const float*)d_in[7];
  const float* c1w  = (const float*)d_in[8];
  const float* c1b  = (const float*)d_in[9];
  const float* c2w  = (const float*)d_in[10];
  const float* c2b  = (const float*)d_in[11];
  const float* c3w  = (const float*)d_in[12];
  const float* c3b  = (const float*)d_in[13];
  const float* p1w  = (const float*)d_in[14];
  const float* p1b  = (const float*)d_in[15];
  const float* p2w  = (const float*)d_in[16];
  const float* p2b  = (const float*)d_in[17];
  const float* p3w  = (const float*)d_in[18];
  const float* p3b  = (const float*)d_in[19];
  const float* fc1w = (const float*)d_in[20];
  const float* fc1b = (const float*)d_in[21];
  const float* fc2w = (const float*)d_in[22];
  const float* fc2b = (const float*)d_in[23];
  const float* fp1w = (const float*)d_in[24];
  const float* fp1b = (const float*)d_in[25];
  const float* fp2w = (const float*)d_in[26];
  const float* fp2b = (const float*)d_in[27];
  const int*   r_idx   = (const int*)d_in[28];
  const int*   a_idx   = (const int*)d_in[29];
  const int*   acc_idx = (const int*)d_in[30];
  const float* rank_q  = (const float*)d_in[31];
  const int*   qlen    = (const int*)d_in[32];
  const int*   rp_idx  = (const int*)d_in[33];
  const int*   ap_idx  = (const int*)d_in[34];
  const float* rank_qp = (const float*)d_in[35];
  const int*   qplen   = (const int*)d_in[36];
  const float* point   = (const float*)d_in[37];
  char* ws = (char*)d_ws;
  if (ws_size < (size_t)WS_END) return;  // not enough scratch: bail (diagnostic)

  prep_kernel<<<2048, 512, 0, stream>>>(
      wihf, whhf, bf_, wihb, whhb, bb_,
      c1w, c1b, c2w, c2b, c3w, c3b,
      p1w, p1b, p2w, p2b, p3w, p3b,
      fc1w, fc1b, fc2w, fc2b, fp1w, fp1b, fp2w, fp2b,
      qlen, qplen, ws);

  lstm_kernel<<<256, 512, 0, stream>>>(rank_q, rank_qp, ws);

  conv_kernel<<<dim3(128, 3), 256, 0, stream>>>(
      ru, au, r_idx, a_idx, acc_idx, rp_idx, ap_idx, ws);

  loss_kernel<<<1, 256, 0, stream>>>(point, ws, (float*)d_out);
}

// Round 2
// 1773.993 us; speedup vs baseline: 1.0044x; 1.0044x over previous
//
#include <hip/hip_runtime.h>
#include <hip/hip_bf16.h>
#include <math.h>

// ---------------------------------------------------------------------------
// RecSys_83391085019409: BiLSTM (fused, persistent per-batch-chunk) + conv/fc
// collapsed into one GEMM per mat + scalar loss.
// B=4096 T=50 D=256 H=128 C=128
// R2: 512 blocks (2/CU, 4 waves/SIMD), 32 rows/block; rcp-based sigm/tanh.
// ---------------------------------------------------------------------------

using short8   = __attribute__((ext_vector_type(8))) short;
using float4_v = __attribute__((ext_vector_type(4))) float;
using ushort4_v= __attribute__((ext_vector_type(4))) unsigned short;

// ---- workspace layout (bytes) ----
#define WS_WC     0u          // bf16 Wc frags: 2 dirs * 12kb*32nt*64lane*8e *2B = 786432
#define WS_BIAS   786432u     // permuted biases: 2*512*4 = 4096
#define WS_WBIG   790528u     // conv big-W frags: 2 sets * 24*48*64*8 *2B = 2359296
#define WS_CBIAS  3149824u    // 2*768*4
#define WS_WPROD  3155968u    // 2*768*4
#define WS_K0     3162112u    // 2 floats (+pad 256)
#define WS_TGT    3162368u    // 4*4096*4 = 65536
#define WS_EMBQ   3227904u    // 4096*256*4
#define WS_EMBQP  7422208u    // 4096*256*4
#define WS_LOW    11616512u   // 4096*4
#define WS_HIGH   11632896u
#define WS_PTS    11649280u
#define WS_END    11665664u

__device__ __forceinline__ unsigned short f2bf(float f) {
  union { float f; unsigned u; } v; v.f = f;
  unsigned r = v.u + 0x7FFFu + ((v.u >> 16) & 1u);
  return (unsigned short)(r >> 16);
}
__device__ __forceinline__ float rcp_f(float x) { return __builtin_amdgcn_rcpf(x); }
__device__ __forceinline__ float sigm(float x) { return rcp_f(1.f + __expf(-x)); }
__device__ __forceinline__ float tanh_f(float x) {
  // tanh(x) = 1 - 2/(e^{2x}+1); exp->inf gives rcp->0 (x>>0 -> 1), exp->0 -> -1.
  return 1.f - 2.f * rcp_f(__expf(2.f * x) + 1.f);
}

// Column permutation for the LSTM gate matrix (N=512):
// m = wblk*64 + g*16 + u  ->  orig n = g*128 + wblk*16 + u
// so each 64-col group holds all 4 gates for 16 hidden units (lane-local gates).
__device__ __forceinline__ int lstm_orig_n(int m) {
  return ((m >> 4) & 3) * 128 + (m >> 6) * 16 + (m & 15);
}

// ---------------------------------------------------------------------------
__global__ void prep_kernel(
    const float* __restrict__ wihf, const float* __restrict__ whhf, const float* __restrict__ bf_,
    const float* __restrict__ wihb, const float* __restrict__ whhb, const float* __restrict__ bb_,
    const float* __restrict__ c1w, const float* __restrict__ c1b,
    const float* __restrict__ c2w, const float* __restrict__ c2b,
    const float* __restrict__ c3w, const float* __restrict__ c3b,
    const float* __restrict__ p1w, const float* __restrict__ p1b,
    const float* __restrict__ p2w, const float* __restrict__ p2b,
    const float* __restrict__ p3w, const float* __restrict__ p3b,
    const float* __restrict__ fc1w, const float* __restrict__ fc1b,
    const float* __restrict__ fc2w, const float* __restrict__ fc2b,
    const float* __restrict__ fp1w, const float* __restrict__ fp1b,
    const float* __restrict__ fp2w, const float* __restrict__ fp2b,
    const int* __restrict__ qlen, const int* __restrict__ qplen,
    char* __restrict__ ws)
{
  unsigned short* wc   = (unsigned short*)(ws + WS_WC);
  float*          bsp  = (float*)(ws + WS_BIAS);
  unsigned short* wbig = (unsigned short*)(ws + WS_WBIG);
  float*          cbias= (float*)(ws + WS_CBIAS);
  float*          wprod= (float*)(ws + WS_WPROD);
  float*          k0   = (float*)(ws + WS_K0);
  int*            tgt  = (int*)(ws + WS_TGT);
  float*          embq = (float*)(ws + WS_EMBQ);
  float*          embqp= (float*)(ws + WS_EMBQP);

  const long N0 = 393216;    // wc elems
  const long N1 = 1024;      // biases
  const long N2 = 1179648;   // wbig elems
  const long N3 = 1536;      // cbias
  const long N4 = 1536;      // wprod
  const long N5 = 16384;     // tgt
  const long N6 = 2097152;   // emb zero
  const long total = N0 + N1 + N2 + N3 + N4 + N5 + N6 + 2;

  for (long i = (long)blockIdx.x * blockDim.x + threadIdx.x; i < total;
       i += (long)gridDim.x * blockDim.x) {
    long idx = i;
    if (idx < N0) {
      long t = idx;
      int e = t & 7; t >>= 3;
      int l = t & 63; t >>= 6;
      int nt = (int)(t % 32); t /= 32;
      int kb = (int)(t % 12); t /= 12;
      int dir = (int)t;
      int k = kb * 32 + (l >> 4) * 8 + e;        // 0..383
      int m = nt * 16 + (l & 15);                // 0..511 (permuted col)
      int n = lstm_orig_n(m);
      const float* wih = dir ? wihb : wihf;
      const float* whh = dir ? whhb : whhf;
      float v = (k < 256) ? wih[n * 256 + k] : whh[n * 128 + (k - 256)];
      wc[idx] = f2bf(v);
    } else if ((idx -= N0) < N1) {
      int dir = (int)(idx >> 9); int m = (int)(idx & 511);
      bsp[idx] = (dir ? bb_ : bf_)[lstm_orig_n(m)];
    } else if ((idx -= N1) < N2) {
      long t = idx;
      int e = t & 7; t >>= 3;
      int l = t & 63; t >>= 6;
      int nt = (int)(t % 48); t /= 48;
      int kb = (int)(t % 24); t /= 24;
      int set = (int)t;
      int k = kb * 32 + (l >> 4) * 8 + e;        // 0..767
      int n = nt * 16 + (l & 15);                // 0..767
      int tau = n >> 7, c = n & 127;
      int r3 = k >> 8, dd = k & 255;
      const float* w1 = set ? p1w : c1w;
      const float* w2 = set ? p2w : c2w;
      const float* w3 = set ? p3w : c3w;
      float v = 0.f;
      if (tau < 3)        { if (r3 == tau) v = w1[c * 256 + dd]; }
      else if (tau == 3)  { if (r3 <= 1)   v = w2[(c * 2 + r3) * 256 + dd]; }
      else if (tau == 4)  { if (r3 >= 1)   v = w2[(c * 2 + r3 - 1) * 256 + dd]; }
      else                {                v = w3[(c * 3 + r3) * 256 + dd]; }
      wbig[idx] = f2bf(v);
    } else if ((idx -= N2) < N3) {
      int set = (int)(idx / 768); int n = (int)(idx % 768);
      int tau = n >> 7, c = n & 127;
      const float* b1 = set ? p1b : c1b;
      const float* b2 = set ? p2b : c2b;
      const float* b3 = set ? p3b : c3b;
      cbias[idx] = (tau < 3) ? b1[c] : (tau < 5 ? b2[c] : b3[c]);
    } else if ((idx -= N3) < N4) {
      int set = (int)(idx / 768); int n = (int)(idx % 768);
      int tau = n >> 7, c = n & 127;
      wprod[idx] = (set ? fp1w : fc1w)[tau] * (set ? fp2w : fc2w)[c];
    } else if ((idx -= N4) < N5) {
      int seqi = (int)(idx >> 13);
      int rem  = (int)(idx & 8191);
      int dir = rem >> 12, b = rem & 4095;
      int L = seqi ? qplen[b] : qlen[b];
      tgt[idx] = (L < 1) ? -1 : (dir ? (50 - L) : (L - 1));
    } else if ((idx -= N5) < N6) {
      if (idx < 1048576) embq[idx] = 0.f; else embqp[idx - 1048576] = 0.f;
    } else {
      idx -= N6;  // 0 or 1 -> K0 constants
      const float* f2 = idx ? fp2w : fc2w;
      float s = 0.f;
      for (int c = 0; c < 128; c++) s += f2[c];
      k0[idx] = (idx ? fp1b[0] : fc1b[0]) * s + (idx ? fp2b[0] : fc2b[0]);
    }
  }
}

// ---------------------------------------------------------------------------
// Fused BiLSTM. grid = 512 blocks: run = blk>>7 (0:q-fwd 1:q-bwd 2:qp-fwd
// 3:qp-bwd), grp = blk&127 owns rows [grp*32, grp*32+32). 512 threads (8
// waves), 2 blocks/CU -> 4 waves/SIMD.
// Wave wv owns all 32 rows x 64 permuted cols [wv*64, wv*64+64)
//   = gates {i,f,g,o} x hidden units [wv*16, wv*16+16)  -> lane-local gates.
// ---------------------------------------------------------------------------
__global__ __launch_bounds__(512, 4) void lstm_kernel(
    const float* __restrict__ rank_q, const float* __restrict__ rank_qp,
    char* __restrict__ ws)
{
  __shared__ unsigned short A_lds[32 * 392];  // 392 shorts/row: 256 x | 128 h | 8 pad
  const int tid  = threadIdx.x;
  const int lane = tid & 63;
  const int wv   = tid >> 6;
  const int l4   = lane >> 4;
  const int lm   = lane & 15;

  const int run   = blockIdx.x >> 7;
  const int grp   = blockIdx.x & 127;
  const int dir   = run & 1;
  const int seqi  = run >> 1;
  const int rowg0 = grp * 32;
  const float* xsrc = seqi ? rank_qp : rank_q;

  const unsigned short* wc = (const unsigned short*)(ws + WS_WC) + (size_t)dir * 196608;
  const float* biasp = (const float*)(ws + WS_BIAS) + dir * 512;
  const int*   tgt   = (const int*)(ws + WS_TGT) + (seqi * 2 + dir) * 4096;
  float*       emb   = (float*)(ws + (seqi ? WS_EMBQP : WS_EMBQ));

  float bv[4];
  #pragma unroll
  for (int g = 0; g < 4; g++) bv[g] = biasp[(wv * 4 + g) * 16 + lm];

  int tg[2][4];
  #pragma unroll
  for (int rti = 0; rti < 2; rti++)
    #pragma unroll
    for (int r = 0; r < 4; r++)
      tg[rti][r] = tgt[rowg0 + rti * 16 + l4 * 4 + r];

  float cst[2][4];
  #pragma unroll
  for (int rti = 0; rti < 2; rti++)
    #pragma unroll
    for (int r = 0; r < 4; r++) cst[rti][r] = 0.f;

  // zero h region (+pad)
  for (int i = tid; i < 32 * 136; i += 512) {
    int rr = i / 136, cc = i - rr * 136;
    A_lds[rr * 392 + 256 + cc] = 0;
  }
  // x staging: each thread owns 16 consecutive floats of one row
  const int rowx = tid >> 4;          // 0..31
  const int dseg = (tid & 15) * 16;   // 0..240
  {
    int t0 = dir ? 49 : 0;
    const float* src = xsrc + ((size_t)(rowg0 + rowx) * 50 + t0) * 256 + dseg;
    #pragma unroll
    for (int j = 0; j < 4; j++) {
      float4_v v = *(const float4_v*)(src + j * 4);
      ushort4_v pk; pk.x = f2bf(v.x); pk.y = f2bf(v.y); pk.z = f2bf(v.z); pk.w = f2bf(v.w);
      *(ushort4_v*)(&A_lds[rowx * 392 + dseg + j * 4]) = pk;
    }
  }
  __syncthreads();

  const int hu = wv * 16 + lm;

  for (int s = 0; s < 50; s++) {
    // prefetch next x-tile into registers (hidden under MFMA phase)
    float4_v xp[4];
    const int sn = s + 1;
    if (sn < 50) {
      int tn = dir ? (49 - sn) : sn;
      const float* src = xsrc + ((size_t)(rowg0 + rowx) * 50 + tn) * 256 + dseg;
      #pragma unroll
      for (int j = 0; j < 4; j++) xp[j] = *(const float4_v*)(src + j * 4);
    }

    float4_v acc[2][4];
    #pragma unroll
    for (int i_ = 0; i_ < 2; i_++)
      #pragma unroll
      for (int j_ = 0; j_ < 4; j_++) acc[i_][j_] = float4_v{0.f, 0.f, 0.f, 0.f};

    #pragma unroll
    for (int kb = 0; kb < 12; kb++) {
      // A frags: row = rt*16 + lm, k = kb*32 + l4*8 + e (same k-map as B)
      short8 a0 = *(const short8*)(&A_lds[( 0 + lm) * 392 + kb * 32 + l4 * 8]);
      short8 a1 = *(const short8*)(&A_lds[(16 + lm) * 392 + kb * 32 + l4 * 8]);
      #pragma unroll
      for (int j = 0; j < 4; j++) {
        const short8 bfrag =
            *(const short8*)(wc + ((size_t)(kb * 32 + wv * 4 + j) * 64 + lane) * 8);
        acc[0][j] = __builtin_amdgcn_mfma_f32_16x16x32_bf16(a0, bfrag, acc[0][j], 0, 0, 0);
        acc[1][j] = __builtin_amdgcn_mfma_f32_16x16x32_bf16(a1, bfrag, acc[1][j], 0, 0, 0);
      }
    }
    __syncthreads();

    // gates: fully lane-local (frag j == gate j for this wave's hu)
    #pragma unroll
    for (int rti = 0; rti < 2; rti++) {
      #pragma unroll
      for (int r = 0; r < 4; r++) {
        float zi = acc[rti][0][r] + bv[0];
        float zf = acc[rti][1][r] + bv[1];
        float zg = acc[rti][2][r] + bv[2];
        float zo = acc[rti][3][r] + bv[3];
        float ig = sigm(zi), fg = sigm(zf), og = sigm(zo);
        float gg = tanh_f(zg);
        float cn = fg * cst[rti][r] + ig * gg;
        cst[rti][r] = cn;
        float hn = og * tanh_f(cn);
        int row = rti * 16 + l4 * 4 + r;
        A_lds[row * 392 + 256 + hu] = f2bf(hn);
        if (s == tg[rti][r])
          emb[(size_t)(rowg0 + row) * 256 + dir * 128 + hu] = hn;
      }
    }
    // stage next x tile
    if (sn < 50) {
      #pragma unroll
      for (int j = 0; j < 4; j++) {
        ushort4_v pk;
        pk.x = f2bf(xp[j].x); pk.y = f2bf(xp[j].y); pk.z = f2bf(xp[j].z); pk.w = f2bf(xp[j].w);
        *(ushort4_v*)(&A_lds[rowx * 392 + dseg + j * 4]) = pk;
      }
    }
    __syncthreads();
  }
}

// ---------------------------------------------------------------------------
// All convs + relu + fc1 + fc2 per mat as one GEMM: [32 rows x 768] @ [768x768]
// with post-ReLU scalar fold (wprod) and per-row reduction.
// grid = (128 row-groups, 3 mats), 256 threads (4 waves).
// ---------------------------------------------------------------------------
__global__ __launch_bounds__(256) void conv_kernel(
    const float* __restrict__ ru, const float* __restrict__ au,
    const int* __restrict__ r_idx, const int* __restrict__ a_idx,
    const int* __restrict__ acc_idx, const int* __restrict__ rp_idx,
    const int* __restrict__ ap_idx, char* __restrict__ ws)
{
  __shared__ unsigned short Atile[32 * 776];   // 768 + 8 pad shorts per row
  __shared__ float red[32][2];
  const int tid = threadIdx.x, lane = tid & 63, wv = tid >> 6;
  const int l4 = lane >> 4, lm = lane & 15;
  const int mgrp = blockIdx.x;
  const int mat  = blockIdx.y;           // 0 low, 1 high, 2 point
  const int set  = (mat == 2) ? 1 : 0;
  const unsigned short* wbig = (const unsigned short*)(ws + WS_WBIG) + (size_t)set * 589824;
  const float* cbias = (const float*)(ws + WS_CBIAS) + set * 768;
  const float* wprod = (const float*)(ws + WS_WPROD) + set * 768;
  const float  K0    = ((const float*)(ws + WS_K0))[set];
  const float* embq  = (const float*)(ws + WS_EMBQ);
  const float* embqp = (const float*)(ws + WS_EMBQP);
  float* outp = (float*)(ws + (mat == 0 ? WS_LOW : (mat == 1 ? WS_HIGH : WS_PTS)));

  const int b0 = mgrp * 32;
  {
    const int rowr = tid >> 3;
    const int seg  = (tid & 7) * 96;
    const int b = b0 + rowr;
    const float *s0, *s1, *s2;
    if (mat == 0)      { s0 = ru + (size_t)r_idx[b] * 256;  s1 = embq  + (size_t)b * 256; s2 = au + (size_t)a_idx[b] * 256; }
    else if (mat == 1) { s0 = ru + (size_t)r_idx[b] * 256;  s1 = embq  + (size_t)b * 256; s2 = au + (size_t)acc_idx[b] * 256; }
    else               { s0 = ru + (size_t)rp_idx[b] * 256; s1 = embqp + (size_t)b * 256; s2 = ru + (size_t)ap_idx[b] * 256; }
    #pragma unroll
    for (int j = 0; j < 24; j++) {
      int k = seg + j * 4;
      int r3 = k >> 8, dd = k & 255;
      const float* src = (r3 == 0) ? s0 : (r3 == 1 ? s1 : s2);
      float4_v v = *(const float4_v*)(src + dd);
      ushort4_v pk; pk.x = f2bf(v.x); pk.y = f2bf(v.y); pk.z = f2bf(v.z); pk.w = f2bf(v.w);
      *(ushort4_v*)(&Atile[rowr * 776 + k]) = pk;
    }
  }
  __syncthreads();

  const int rt  = wv & 1;
  const int ntb = (wv >> 1) * 24;
  float4_v acc[24];
  #pragma unroll
  for (int j = 0; j < 24; j++) acc[j] = float4_v{0.f, 0.f, 0.f, 0.f};
  const int arow = rt * 16 + lm;
  #pragma unroll 1
  for (int kb = 0; kb < 24; kb++) {
    short8 a = *(const short8*)(&Atile[arow * 776 + kb * 32 + l4 * 8]);
    #pragma unroll
    for (int j = 0; j < 24; j++) {
      short8 bfrag = *(const short8*)(wbig + ((size_t)(kb * 48 + ntb + j) * 64 + lane) * 8);
      acc[j] = __builtin_amdgcn_mfma_f32_16x16x32_bf16(a, bfrag, acc[j], 0, 0, 0);
    }
  }
  float rs[4] = {0.f, 0.f, 0.f, 0.f};
  #pragma unroll
  for (int j = 0; j < 24; j++) {
    int n = (ntb + j) * 16 + lm;
    float cb = cbias[n], wp = wprod[n];
    #pragma unroll
    for (int r = 0; r < 4; r++)
      rs[r] += fmaxf(acc[j][r] + cb, 0.f) * wp;
  }
  #pragma unroll
  for (int r = 0; r < 4; r++) {
    float v = rs[r];
    v += __shfl_xor(v, 1);
    v += __shfl_xor(v, 2);
    v += __shfl_xor(v, 4);
    v += __shfl_xor(v, 8);
    rs[r] = v;
  }
  if (lm == 0) {
    int rloc = rt * 16 + l4 * 4;
    #pragma unroll
    for (int r = 0; r < 4; r++) red[rloc + r][wv >> 1] = rs[r];
  }
  __syncthreads();
  if (tid < 32) outp[b0 + tid] = red[tid][0] + red[tid][1] + K0;
}

// ---------------------------------------------------------------------------
__global__ void loss_kernel(const float* __restrict__ point, char* __restrict__ ws,
                            float* __restrict__ out)
{
  __shared__ float ra[256], rb[256];
  const float* low  = (const float*)(ws + WS_LOW);
  const float* high = (const float*)(ws + WS_HIGH);
  const float* pts  = (const float*)(ws + WS_PTS);
  int tid = threadIdx.x;
  float a = 0.f, b = 0.f;
  for (int i = tid; i < 4096; i += 256) {
    a += sigm(low[i] - high[i]);
    b += sigm(fabsf(pts[i] - point[i]));
  }
  ra[tid] = a; rb[tid] = b;
  __syncthreads();
  for (int off = 128; off > 0; off >>= 1) {
    if (tid < off) { ra[tid] += ra[tid + off]; rb[tid] += rb[tid + off]; }
    __syncthreads();
  }
  if (tid == 0) out[0] = 0.8f * ra[0] + 0.2f * rb[0];
}

// ---------------------------------------------------------------------------
extern "C" void kernel_launch(void* const* d_in, const int* in_sizes, int n_in,
                              void* d_out, int out_size, void* d_ws, size_t ws_size,
                              hipStream_t stream) {
  (void)in_sizes; (void)n_in; (void)out_size;
  const float* ru   = (const float*)d_in[0];
  const float* au   = (const float*)d_in[1];
  const float* wihf = (const float*)d_in[2];
  const float* whhf = (const float*)d_in[3];
  const float* bf_  = (const float*)d_in[4];
  const float* wihb = (const float*)d_in[5];
  const float* whhb = (const float*)d_in[6];
  const float* bb_  = (const float*)d_in[7];
  const float* c1w  = (const float*)d_in[8];
  const float* c1b  = (const float*)d_in[9];
  const float* c2w  = (const float*)d_in[10];
  const float* c2b  = (const float*)d_in[11];
  const float* c3w  = (const float*)d_in[12];
  const float* c3b  = (const float*)d_in[13];
  const float* p1w  = (const float*)d_in[14];
  const float* p1b  = (const float*)d_in[15];
  const float* p2w  = (const float*)d_in[16];
  const float* p2b  = (const float*)d_in[17];
  const float* p3w  = (const float*)d_in[18];
  const float* p3b  = (const float*)d_in[19];
  const float* fc1w = (const float*)d_in[20];
  const float* fc1b = (const float*)d_in[21];
  const float* fc2w = (const float*)d_in[22];
  const float* fc2b = (const float*)d_in[23];
  const float* fp1w = (const float*)d_in[24];
  const float* fp1b = (const float*)d_in[25];
  const float* fp2w = (const float*)d_in[26];
  const float* fp2b = (const float*)d_in[27];
  const int*   r_idx   = (const int*)d_in[28];
  const int*   a_idx   = (const int*)d_in[29];
  const int*   acc_idx = (const int*)d_in[30];
  const float* rank_q  = (const float*)d_in[31];
  const int*   qlen    = (const int*)d_in[32];
  const int*   rp_idx  = (const int*)d_in[33];
  const int*   ap_idx  = (const int*)d_in[34];
  const float* rank_qp = (const float*)d_in[35];
  const int*   qplen   = (const int*)d_in[36];
  const float* point   = (const float*)d_in[37];
  char* ws = (char*)d_ws;
  if (ws_size < (size_t)WS_END) return;  // not enough scratch: bail (diagnostic)

  prep_kernel<<<2048, 512, 0, stream>>>(
      wihf, whhf, bf_, wihb, whhb, bb_,
      c1w, c1b, c2w, c2b, c3w, c3b,
      p1w, p1b, p2w, p2b, p3w, p3b,
      fc1w, fc1b, fc2w, fc2b, fp1w, fp1b, fp2w, fp2b,
      qlen, qplen, ws);

  lstm_kernel<<<512, 512, 0, stream>>>(rank_q, rank_qp, ws);

  conv_kernel<<<dim3(128, 3), 256, 0, stream>>>(
      ru, au, r_idx, a_idx, acc_idx, rp_idx, ap_idx, ws);

  loss_kernel<<<1, 256, 0, stream>>>(point, ws, (float*)d_out);
}